// Round 1
// baseline (303.243 us; speedup 1.0000x reference)
//
#include <hip/hip_runtime.h>
#include <stdint.h>
#include <stddef.h>

#define SEQ 4096
#define DIM 1024

typedef __bf16 bf16x8 __attribute__((ext_vector_type(8)));
typedef float floatx4 __attribute__((ext_vector_type(4)));
typedef unsigned short u16x8 __attribute__((ext_vector_type(8)));

__device__ __forceinline__ unsigned short f2b(float f) {
  union { float f; unsigned u; } v; v.f = f;
  unsigned u = v.u;
  unsigned r = (u + 0x7FFFu + ((u >> 16) & 1u)) >> 16;
  return (unsigned short)r;
}
__device__ __forceinline__ float b2f(unsigned short h) {
  union { unsigned u; float f; } v; v.u = ((unsigned)h) << 16;
  return v.f;
}

// ---------------- fp32 -> bf16 convert ----------------
__global__ void cvt_f32_bf16(const float* __restrict__ in,
                             unsigned short* __restrict__ out, int n) {
  int i = (blockIdx.x * blockDim.x + threadIdx.x) * 4;
  if (i < n) {
    float4 f = *(const float4*)(in + i);
    ushort4 o;
    o.x = f2b(f.x); o.y = f2b(f.y); o.z = f2b(f.z); o.w = f2b(f.w);
    *(ushort4*)(out + i) = o;
  }
}

// ---------------- B^T-form bf16 GEMM: C[M,N] = A[M,K] * B[N,K]^T ----------------
// MODE 0: bf16 out [M,N], + bias[n]
// MODE 1: bf16 out transposed [N,SEQ], + bias[n]   (for V -> V^T)
// MODE 2: bf16 out [M,N], * scale                  (scores)
// MODE 3: f32  out [M,N]                           (PV -> d_out)
template <int MODE>
__global__ __launch_bounds__(256, 2)
void gemm_bt(const unsigned short* __restrict__ A,
             const unsigned short* __restrict__ B,
             const float* __restrict__ bias,
             void* __restrict__ Cout,
             int N, int K, float scale) {
  __shared__ unsigned short As[128 * 64];
  __shared__ unsigned short Bs[128 * 64];

  const int tid  = threadIdx.x;
  const int lane = tid & 63;
  const int wave = tid >> 6;
  const int tile_m = blockIdx.y * 128;
  const int tile_n = blockIdx.x * 128;
  const int sub_m = (wave >> 1) * 64;
  const int sub_n = (wave & 1) * 64;
  const int col  = lane & 15;
  const int quad = lane >> 4;

  floatx4 acc[4][4];
#pragma unroll
  for (int i = 0; i < 4; i++)
#pragma unroll
    for (int j = 0; j < 4; j++) acc[i][j] = (floatx4)0.0f;

  // staging: 128x64 bf16 tile = 8192 elts; 256 thr * 8 elts = 2048/step, 4 steps
  const int flat = tid * 8;       // 0..2047
  const int srow = flat >> 6;     // 0..31
  const int scol = flat & 63;

  const unsigned short* Ag = A + (size_t)(tile_m + srow) * K + scol;
  const unsigned short* Bg = B + (size_t)(tile_n + srow) * K + scol;

  for (int k0 = 0; k0 < K; k0 += 64) {
    __syncthreads();   // previous iteration's readers done before overwrite
#pragma unroll
    for (int j = 0; j < 4; j++) {
      __builtin_amdgcn_global_load_lds(
          (const __attribute__((address_space(1))) void*)(Ag + (size_t)j * 32 * K + k0),
          (__attribute__((address_space(3))) void*)(&As[j * 2048 + flat]), 16, 0, 0);
      __builtin_amdgcn_global_load_lds(
          (const __attribute__((address_space(1))) void*)(Bg + (size_t)j * 32 * K + k0),
          (__attribute__((address_space(3))) void*)(&Bs[j * 2048 + flat]), 16, 0, 0);
    }
    __syncthreads();   // drains vmcnt (global_load_lds) + makes LDS visible
#pragma unroll
    for (int ks = 0; ks < 64; ks += 32) {
      bf16x8 af[4], bfr[4];
#pragma unroll
      for (int i = 0; i < 4; i++)
        af[i] = *(const bf16x8*)&As[(sub_m + 16 * i + col) * 64 + ks + quad * 8];
#pragma unroll
      for (int j = 0; j < 4; j++)
        bfr[j] = *(const bf16x8*)&Bs[(sub_n + 16 * j + col) * 64 + ks + quad * 8];
#pragma unroll
      for (int i = 0; i < 4; i++)
#pragma unroll
        for (int j = 0; j < 4; j++)
          acc[i][j] = __builtin_amdgcn_mfma_f32_16x16x32_bf16(af[i], bfr[j],
                                                              acc[i][j], 0, 0, 0);
    }
  }

  // epilogue — C/D layout: col = lane&15, row = quad*4 + reg  [verified m89/m91]
  float biasv[4];
  if constexpr (MODE == 0 || MODE == 1) {
#pragma unroll
    for (int j = 0; j < 4; j++)
      biasv[j] = bias[tile_n + sub_n + 16 * j + col];
  }
#pragma unroll
  for (int i = 0; i < 4; i++) {
#pragma unroll
    for (int j = 0; j < 4; j++) {
#pragma unroll
      for (int r = 0; r < 4; r++) {
        const int m = tile_m + sub_m + 16 * i + quad * 4 + r;
        const int n = tile_n + sub_n + 16 * j + col;
        const float v = acc[i][j][r];
        if constexpr (MODE == 0) {
          ((unsigned short*)Cout)[(size_t)m * N + n] = f2b(v + biasv[j]);
        } else if constexpr (MODE == 1) {
          ((unsigned short*)Cout)[(size_t)n * SEQ + m] = f2b(v + biasv[j]);
        } else if constexpr (MODE == 2) {
          ((unsigned short*)Cout)[(size_t)m * N + n] = f2b(v * scale);
        } else {
          ((float*)Cout)[(size_t)m * N + n] = v;
        }
      }
    }
  }
}

// ---------------- in-place row softmax on bf16 [SEQ, SEQ] ----------------
__global__ __launch_bounds__(256)
void softmax_inplace(unsigned short* __restrict__ P) {
  const int row = blockIdx.x;
  unsigned short* p = P + (size_t)row * SEQ;
  const int tid  = threadIdx.x;
  const int lane = tid & 63;
  const int wave = tid >> 6;

  u16x8 raw0 = *(const u16x8*)(p + tid * 16);
  u16x8 raw1 = *(const u16x8*)(p + tid * 16 + 8);
  float v[16];
#pragma unroll
  for (int k = 0; k < 8; k++) v[k] = b2f(raw0[k]);
#pragma unroll
  for (int k = 0; k < 8; k++) v[8 + k] = b2f(raw1[k]);

  float mx = -1e30f;
#pragma unroll
  for (int k = 0; k < 16; k++) mx = fmaxf(mx, v[k]);
#pragma unroll
  for (int off = 32; off > 0; off >>= 1) mx = fmaxf(mx, __shfl_xor(mx, off, 64));
  __shared__ float redm[4];
  __shared__ float reds[4];
  if (lane == 0) redm[wave] = mx;
  __syncthreads();
  mx = fmaxf(fmaxf(redm[0], redm[1]), fmaxf(redm[2], redm[3]));

  float sum = 0.0f;
#pragma unroll
  for (int k = 0; k < 16; k++) {
    v[k] = exp2f((v[k] - mx) * 1.44269504f);
    sum += v[k];
  }
#pragma unroll
  for (int off = 32; off > 0; off >>= 1) sum += __shfl_xor(sum, off, 64);
  if (lane == 0) reds[wave] = sum;
  __syncthreads();
  sum = reds[0] + reds[1] + reds[2] + reds[3];
  const float inv = 1.0f / sum;

  u16x8 o0, o1;
#pragma unroll
  for (int k = 0; k < 8; k++) o0[k] = f2b(v[k] * inv);
#pragma unroll
  for (int k = 0; k < 8; k++) o1[k] = f2b(v[8 + k] * inv);
  *(u16x8*)(p + tid * 16) = o0;
  *(u16x8*)(p + tid * 16 + 8) = o1;
}

extern "C" void kernel_launch(void* const* d_in, const int* in_sizes, int n_in,
                              void* d_out, int out_size, void* d_ws, size_t ws_size,
                              hipStream_t stream) {
  const float* x  = (const float*)d_in[0];
  const float* wq = (const float*)d_in[1];
  const float* bq = (const float*)d_in[2];
  const float* wk = (const float*)d_in[3];
  const float* bk = (const float*)d_in[4];
  const float* wv = (const float*)d_in[5];
  const float* bv = (const float*)d_in[6];

  uint8_t* ws = (uint8_t*)d_ws;
  // workspace layout (70 MiB total)
  unsigned short* xb  = (unsigned short*)(ws);                      // 8 MiB
  unsigned short* wqb = (unsigned short*)(ws + ((size_t)8  << 20)); // 2 MiB
  unsigned short* wkb = (unsigned short*)(ws + ((size_t)10 << 20)); // 2 MiB
  unsigned short* wvb = (unsigned short*)(ws + ((size_t)12 << 20)); // 2 MiB
  unsigned short* qb  = (unsigned short*)(ws + ((size_t)14 << 20)); // 8 MiB
  unsigned short* kb  = (unsigned short*)(ws + ((size_t)22 << 20)); // 8 MiB
  unsigned short* vtb = (unsigned short*)(ws + ((size_t)30 << 20)); // 8 MiB  (V^T [DIM][SEQ])
  unsigned short* sc  = (unsigned short*)(ws + ((size_t)38 << 20)); // 32 MiB (scores/attn)

  // fp32 -> bf16
  cvt_f32_bf16<<<(SEQ * DIM) / 1024, 256, 0, stream>>>(x, xb, SEQ * DIM);
  cvt_f32_bf16<<<(DIM * DIM) / 1024, 256, 0, stream>>>(wq, wqb, DIM * DIM);
  cvt_f32_bf16<<<(DIM * DIM) / 1024, 256, 0, stream>>>(wk, wkb, DIM * DIM);
  cvt_f32_bf16<<<(DIM * DIM) / 1024, 256, 0, stream>>>(wv, wvb, DIM * DIM);

  // Q = x*wq^T + bq ; K = x*wk^T + bk ; V^T = (x*wv^T + bv)^T
  gemm_bt<0><<<dim3(DIM / 128, SEQ / 128), 256, 0, stream>>>(xb, wqb, bq, qb, DIM, DIM, 1.0f);
  gemm_bt<0><<<dim3(DIM / 128, SEQ / 128), 256, 0, stream>>>(xb, wkb, bk, kb, DIM, DIM, 1.0f);
  gemm_bt<1><<<dim3(DIM / 128, SEQ / 128), 256, 0, stream>>>(xb, wvb, bv, vtb, DIM, DIM, 1.0f);

  // scores = (Q K^T) / sqrt(D)
  gemm_bt<2><<<dim3(SEQ / 128, SEQ / 128), 256, 0, stream>>>(qb, kb, nullptr, sc, SEQ, DIM, 0.03125f);

  // softmax rows in place
  softmax_inplace<<<SEQ, 256, 0, stream>>>(sc);

  // out = attn @ V  =  attn * (V^T)^T   (fp32 store)
  gemm_bt<3><<<dim3(DIM / 128, SEQ / 128), 256, 0, stream>>>(sc, vtb, nullptr, (float*)d_out, DIM, SEQ, 1.0f);
}

// Round 2
// 220.514 us; speedup vs baseline: 1.3752x; 1.3752x over previous
//
#include <hip/hip_runtime.h>
#include <stdint.h>
#include <stddef.h>

#define SEQ 4096
#define DIM 1024

typedef __bf16 bf16x8 __attribute__((ext_vector_type(8)));
typedef float floatx4 __attribute__((ext_vector_type(4)));
typedef unsigned short u16x8 __attribute__((ext_vector_type(8)));

__device__ __forceinline__ unsigned short f2b(float f) {
  union { float f; unsigned u; } v; v.f = f;
  unsigned u = v.u;
  unsigned r = (u + 0x7FFFu + ((u >> 16) & 1u)) >> 16;
  return (unsigned short)r;
}
__device__ __forceinline__ float b2f(unsigned short h) {
  union { unsigned u; float f; } v; v.u = ((unsigned)h) << 16;
  return v.f;
}

// ---------------- fp32 -> bf16 convert ----------------
__global__ void cvt_f32_bf16(const float* __restrict__ in,
                             unsigned short* __restrict__ out, int n) {
  int i = (blockIdx.x * blockDim.x + threadIdx.x) * 4;
  if (i < n) {
    float4 f = *(const float4*)(in + i);
    ushort4 o;
    o.x = f2b(f.x); o.y = f2b(f.y); o.z = f2b(f.z); o.w = f2b(f.w);
    *(ushort4*)(out + i) = o;
  }
}

// ---------------- core 128x128 B^T-form bf16 tile GEMM ----------------
// C_tile[128,128] += A[tile_m:+128, :kext] * B[tile_n:+128, :kext]^T
// A,B already offset to the tile's first row (and K-chunk).
// LDS layout XOR-swizzled: granule g (8 elts) of row r stored at slot g^(r&7).
// Writer swizzles the SOURCE column (global_load_lds dest is lane-ordered);
// each 8-lane group still covers one contiguous 128 B global segment.
__device__ __forceinline__ void gemm_core(
    const unsigned short* __restrict__ A,
    const unsigned short* __restrict__ B,
    int lda, int ldb, int kext,
    unsigned short* As, unsigned short* Bs,
    floatx4 acc[4][4]) {
  const int tid  = threadIdx.x;
  const int lane = tid & 63;
  const int wave = tid >> 6;
  const int sub_m = (wave >> 1) * 64;
  const int sub_n = (wave & 1) * 64;
  const int col  = lane & 15;
  const int quad = lane >> 4;

  const int srow  = tid >> 3;                  // 0..31 (row within 32-row step)
  const int sgran = (tid & 7) ^ (srow & 7);    // swizzled source granule
  const int scol  = sgran * 8;
  const int dflat = tid * 8;                   // LDS dest (lane-ordered, fixed)

  const unsigned short* Ag = A + (size_t)srow * lda + scol;
  const unsigned short* Bg = B + (size_t)srow * ldb + scol;

  for (int k0 = 0; k0 < kext; k0 += 64) {
    __syncthreads();   // previous iteration's readers done before overwrite
#pragma unroll
    for (int j = 0; j < 4; j++) {
      __builtin_amdgcn_global_load_lds(
          (const __attribute__((address_space(1))) void*)(Ag + (size_t)(j * 32) * lda + k0),
          (__attribute__((address_space(3))) void*)(&As[j * 2048 + dflat]), 16, 0, 0);
      __builtin_amdgcn_global_load_lds(
          (const __attribute__((address_space(1))) void*)(Bg + (size_t)(j * 32) * ldb + k0),
          (__attribute__((address_space(3))) void*)(&Bs[j * 2048 + dflat]), 16, 0, 0);
    }
    __syncthreads();   // drains vmcnt + makes LDS visible
#pragma unroll
    for (int ks = 0; ks < 64; ks += 32) {
      const int gbase = ks >> 3;   // 0 or 4
      bf16x8 af[4], bfr[4];
#pragma unroll
      for (int i = 0; i < 4; i++) {
        const int R = sub_m + 16 * i + col;
        const int slot = (gbase + quad) ^ (R & 7);
        af[i] = *(const bf16x8*)&As[R * 64 + slot * 8];
      }
#pragma unroll
      for (int j = 0; j < 4; j++) {
        const int R = sub_n + 16 * j + col;
        const int slot = (gbase + quad) ^ (R & 7);
        bfr[j] = *(const bf16x8*)&Bs[R * 64 + slot * 8];
      }
#pragma unroll
      for (int i = 0; i < 4; i++)
#pragma unroll
        for (int j = 0; j < 4; j++)
          acc[i][j] = __builtin_amdgcn_mfma_f32_16x16x32_bf16(af[i], bfr[j],
                                                              acc[i][j], 0, 0, 0);
    }
  }
}

// C/D layout: col = lane&15, row = quad*4 + reg   [verified m89/m91]

// ---------------- fused QKV: z=0 Q, z=1 K, z=2 V(transposed store) ----------------
__global__ __launch_bounds__(256, 2)
void qkv_gemm(const unsigned short* __restrict__ xb,
              const unsigned short* __restrict__ wqb,
              const unsigned short* __restrict__ wkb,
              const unsigned short* __restrict__ wvb,
              const float* __restrict__ bq, const float* __restrict__ bk,
              const float* __restrict__ bv,
              unsigned short* __restrict__ qb, unsigned short* __restrict__ kb,
              unsigned short* __restrict__ vtb) {
  __shared__ unsigned short As[8192];
  __shared__ unsigned short Bs[8192];
  const int z = blockIdx.z;
  const unsigned short* W = (z == 0) ? wqb : (z == 1) ? wkb : wvb;
  const float* bias = (z == 0) ? bq : (z == 1) ? bk : bv;
  const int tile_m = blockIdx.y * 128;
  const int tile_n = blockIdx.x * 128;

  floatx4 acc[4][4];
#pragma unroll
  for (int i = 0; i < 4; i++)
#pragma unroll
    for (int j = 0; j < 4; j++) acc[i][j] = (floatx4)0.0f;

  gemm_core(xb + (size_t)tile_m * DIM, W + (size_t)tile_n * DIM,
            DIM, DIM, DIM, As, Bs, acc);

  const int lane = threadIdx.x & 63;
  const int wave = threadIdx.x >> 6;
  const int sub_m = (wave >> 1) * 64;
  const int sub_n = (wave & 1) * 64;
  const int col  = lane & 15;
  const int quad = lane >> 4;

  float biasv[4];
#pragma unroll
  for (int j = 0; j < 4; j++) biasv[j] = bias[tile_n + sub_n + 16 * j + col];

  unsigned short* outp = (z == 0) ? qb : kb;
#pragma unroll
  for (int i = 0; i < 4; i++) {
#pragma unroll
    for (int j = 0; j < 4; j++) {
#pragma unroll
      for (int r = 0; r < 4; r++) {
        const int m = tile_m + sub_m + 16 * i + quad * 4 + r;
        const int n = tile_n + sub_n + 16 * j + col;
        const unsigned short v = f2b(acc[i][j][r] + biasv[j]);
        if (z < 2)
          outp[(size_t)m * DIM + n] = v;
        else
          vtb[(size_t)n * SEQ + m] = v;   // V^T [DIM, SEQ]
      }
    }
  }
}

// ---------------- scores = (Q K^T) * scale, bf16 out ----------------
__global__ __launch_bounds__(256, 2)
void score_gemm(const unsigned short* __restrict__ qb,
                const unsigned short* __restrict__ kb,
                unsigned short* __restrict__ sc, float scale) {
  __shared__ unsigned short As[8192];
  __shared__ unsigned short Bs[8192];
  const int tile_m = blockIdx.y * 128;
  const int tile_n = blockIdx.x * 128;

  floatx4 acc[4][4];
#pragma unroll
  for (int i = 0; i < 4; i++)
#pragma unroll
    for (int j = 0; j < 4; j++) acc[i][j] = (floatx4)0.0f;

  gemm_core(qb + (size_t)tile_m * DIM, kb + (size_t)tile_n * DIM,
            DIM, DIM, DIM, As, Bs, acc);

  const int lane = threadIdx.x & 63;
  const int wave = threadIdx.x >> 6;
  const int sub_m = (wave >> 1) * 64;
  const int sub_n = (wave & 1) * 64;
  const int col  = lane & 15;
  const int quad = lane >> 4;
#pragma unroll
  for (int i = 0; i < 4; i++) {
#pragma unroll
    for (int j = 0; j < 4; j++) {
#pragma unroll
      for (int r = 0; r < 4; r++) {
        const int m = tile_m + sub_m + 16 * i + quad * 4 + r;
        const int n = tile_n + sub_n + 16 * j + col;
        sc[(size_t)m * SEQ + n] = f2b(acc[i][j][r] * scale);
      }
    }
  }
}

// ---------------- PV split-K=2: z=0 -> d_out, z=1 -> partial ----------------
__global__ __launch_bounds__(256, 2)
void pv_gemm(const unsigned short* __restrict__ sc,
             const unsigned short* __restrict__ vtb,
             float* __restrict__ out0, float* __restrict__ out1) {
  __shared__ unsigned short As[8192];
  __shared__ unsigned short Bs[8192];
  const int z = blockIdx.z;
  const int koff = z * (SEQ / 2);
  float* C = z ? out1 : out0;
  const int tile_m = blockIdx.y * 128;
  const int tile_n = blockIdx.x * 128;

  floatx4 acc[4][4];
#pragma unroll
  for (int i = 0; i < 4; i++)
#pragma unroll
    for (int j = 0; j < 4; j++) acc[i][j] = (floatx4)0.0f;

  gemm_core(sc + (size_t)tile_m * SEQ + koff,
            vtb + (size_t)tile_n * SEQ + koff,
            SEQ, SEQ, SEQ / 2, As, Bs, acc);

  const int lane = threadIdx.x & 63;
  const int wave = threadIdx.x >> 6;
  const int sub_m = (wave >> 1) * 64;
  const int sub_n = (wave & 1) * 64;
  const int col  = lane & 15;
  const int quad = lane >> 4;
#pragma unroll
  for (int i = 0; i < 4; i++) {
#pragma unroll
    for (int j = 0; j < 4; j++) {
#pragma unroll
      for (int r = 0; r < 4; r++) {
        const int m = tile_m + sub_m + 16 * i + quad * 4 + r;
        const int n = tile_n + sub_n + 16 * j + col;
        C[(size_t)m * DIM + n] = acc[i][j][r];
      }
    }
  }
}

// ---------------- out += partial ----------------
__global__ __launch_bounds__(256)
void reduce_add(float* __restrict__ out, const float* __restrict__ part) {
  const int i = (blockIdx.x * 256 + threadIdx.x) * 4;
  float4 a = *(const float4*)(out + i);
  float4 b = *(const float4*)(part + i);
  a.x += b.x; a.y += b.y; a.z += b.z; a.w += b.w;
  *(float4*)(out + i) = a;
}

// ---------------- in-place row softmax on bf16 [SEQ, SEQ] ----------------
__global__ __launch_bounds__(256)
void softmax_inplace(unsigned short* __restrict__ P) {
  const int row = blockIdx.x;
  unsigned short* p = P + (size_t)row * SEQ;
  const int tid  = threadIdx.x;
  const int lane = tid & 63;
  const int wave = tid >> 6;

  u16x8 raw0 = *(const u16x8*)(p + tid * 16);
  u16x8 raw1 = *(const u16x8*)(p + tid * 16 + 8);
  float v[16];
#pragma unroll
  for (int k = 0; k < 8; k++) v[k] = b2f(raw0[k]);
#pragma unroll
  for (int k = 0; k < 8; k++) v[8 + k] = b2f(raw1[k]);

  float mx = -1e30f;
#pragma unroll
  for (int k = 0; k < 16; k++) mx = fmaxf(mx, v[k]);
#pragma unroll
  for (int off = 32; off > 0; off >>= 1) mx = fmaxf(mx, __shfl_xor(mx, off, 64));
  __shared__ float redm[4];
  __shared__ float reds[4];
  if (lane == 0) redm[wave] = mx;
  __syncthreads();
  mx = fmaxf(fmaxf(redm[0], redm[1]), fmaxf(redm[2], redm[3]));

  float sum = 0.0f;
#pragma unroll
  for (int k = 0; k < 16; k++) {
    v[k] = exp2f((v[k] - mx) * 1.44269504f);
    sum += v[k];
  }
#pragma unroll
  for (int off = 32; off > 0; off >>= 1) sum += __shfl_xor(sum, off, 64);
  if (lane == 0) reds[wave] = sum;
  __syncthreads();
  sum = reds[0] + reds[1] + reds[2] + reds[3];
  const float inv = 1.0f / sum;

  u16x8 o0, o1;
#pragma unroll
  for (int k = 0; k < 8; k++) o0[k] = f2b(v[k] * inv);
#pragma unroll
  for (int k = 0; k < 8; k++) o1[k] = f2b(v[8 + k] * inv);
  *(u16x8*)(p + tid * 16) = o0;
  *(u16x8*)(p + tid * 16 + 8) = o1;
}

extern "C" void kernel_launch(void* const* d_in, const int* in_sizes, int n_in,
                              void* d_out, int out_size, void* d_ws, size_t ws_size,
                              hipStream_t stream) {
  const float* x  = (const float*)d_in[0];
  const float* wq = (const float*)d_in[1];
  const float* bq = (const float*)d_in[2];
  const float* wk = (const float*)d_in[3];
  const float* bk = (const float*)d_in[4];
  const float* wv = (const float*)d_in[5];
  const float* bv = (const float*)d_in[6];

  uint8_t* ws = (uint8_t*)d_ws;
  // workspace layout (70 MiB total; `part` aliases the region dead by PV time)
  unsigned short* xb  = (unsigned short*)(ws);                      // [0,8)   MiB
  unsigned short* wqb = (unsigned short*)(ws + ((size_t)8  << 20)); // [8,10)
  unsigned short* wkb = (unsigned short*)(ws + ((size_t)10 << 20)); // [10,12)
  unsigned short* wvb = (unsigned short*)(ws + ((size_t)12 << 20)); // [12,14)
  unsigned short* qb  = (unsigned short*)(ws + ((size_t)14 << 20)); // [14,22)
  unsigned short* kb  = (unsigned short*)(ws + ((size_t)22 << 20)); // [22,30)
  unsigned short* vtb = (unsigned short*)(ws + ((size_t)30 << 20)); // [30,38)  V^T [DIM][SEQ]
  unsigned short* sc  = (unsigned short*)(ws + ((size_t)38 << 20)); // [38,70)  scores/attn
  float*          part = (float*)(ws);                              // [0,16)   PV k-chunk-1 partial

  // fp32 -> bf16
  cvt_f32_bf16<<<(SEQ * DIM) / 1024, 256, 0, stream>>>(x, xb, SEQ * DIM);
  cvt_f32_bf16<<<(DIM * DIM) / 1024, 256, 0, stream>>>(wq, wqb, DIM * DIM);
  cvt_f32_bf16<<<(DIM * DIM) / 1024, 256, 0, stream>>>(wk, wkb, DIM * DIM);
  cvt_f32_bf16<<<(DIM * DIM) / 1024, 256, 0, stream>>>(wv, wvb, DIM * DIM);

  // fused Q/K/V^T projection (768 blocks -> 3 blocks/CU)
  qkv_gemm<<<dim3(DIM / 128, SEQ / 128, 3), 256, 0, stream>>>(
      xb, wqb, wkb, wvb, bq, bk, bv, qb, kb, vtb);

  // scores = (Q K^T) / sqrt(D)   (1024 blocks)
  score_gemm<<<dim3(SEQ / 128, SEQ / 128), 256, 0, stream>>>(qb, kb, sc, 0.03125f);

  // softmax rows in place
  softmax_inplace<<<SEQ, 256, 0, stream>>>(sc);

  // out = attn @ V, split-K=2 (512 blocks): chunk0 -> d_out, chunk1 -> part
  pv_gemm<<<dim3(DIM / 128, SEQ / 128, 2), 256, 0, stream>>>(
      sc, vtb, (float*)d_out, part);

  // d_out += part
  reduce_add<<<(SEQ * DIM) / 1024, 256, 0, stream>>>((float*)d_out, part);
}